// Round 19
// baseline (148.784 us; speedup 1.0000x reference)
//
#include <hip/hip_runtime.h>
#include <hip/hip_bf16.h>
#include <math.h>

// B=2, C=128, H=W=64, heads=4, head_dim=32, kernel=7 (49 taps), depth=2.
// Inputs fp32, OUTPUT fp32. Intermediates bf16. MFMA GEMMs.
// R19 = R18 with na_attn v7: 4x4 tile x 2 heads, 4 dims/lane (r=0..7),
// 1024 blocks -> 4 blocks/CU, 16 waves/CU (2x v6's wave count).
#define PIX 8192
typedef __hip_bfloat16 bf16;
typedef __attribute__((ext_vector_type(8))) short short8;
typedef __attribute__((ext_vector_type(4))) float f32x4;

__device__ inline float bflo(unsigned u) { return __uint_as_float(u << 16); }
__device__ inline float bfhi(unsigned u) { return __uint_as_float(u & 0xffff0000u); }
__device__ inline unsigned short f2b(float f) {
  __hip_bfloat16 h = __float2bfloat16(f);
  return *reinterpret_cast<unsigned short*>(&h);
}
__device__ inline unsigned pack2(float a, float b) {
  return (unsigned)f2b(a) | ((unsigned)f2b(b) << 16);
}

// ---------- weight conversion fp32 -> bf16 ----------
__global__ __launch_bounds__(256) void cvtw(const float* __restrict__ qw,
                                            const float* __restrict__ pw,
                                            unsigned short* __restrict__ wq,
                                            unsigned short* __restrict__ wp) {
  int idx = blockIdx.x * 256 + threadIdx.x;   // 384 blocks -> 98304
  if (idx < 98304) wq[idx] = f2b(qw[idx]);
  if (idx < 32768) wp[idx] = f2b(pw[idx]);
}

// ---------- fused transpose + qkv0: x (NCHW fp32) -> qkv (bf16) ----------
__global__ __launch_bounds__(256) void xqkv(const float* __restrict__ x,
                                            const unsigned short* __restrict__ wq,
                                            const float* __restrict__ qb,
                                            unsigned short* __restrict__ qkv) {
  __shared__ __align__(16) unsigned short As[16 * 136];
  int m0 = blockIdx.x * 16;
  int tid = threadIdx.x;
  int b = m0 >> 12, i = (m0 >> 6) & 63, j0 = m0 & 63;

  for (int idx = tid; idx < 2048; idx += 256) {
    int c = idx >> 4, jl = idx & 15;
    As[jl * 136 + c] =
        f2b(x[(size_t)b * 524288 + (size_t)c * 4096 + i * 64 + j0 + jl]);
  }
  __syncthreads();

  int w = tid >> 6, lane = tid & 63;
  int quad = lane >> 4, l16 = lane & 15;
  short8 a[4];
#pragma unroll
  for (int kc = 0; kc < 4; ++kc)
    a[kc] = *(const short8*)(As + l16 * 136 + kc * 32 + quad * 8);
#pragma unroll
  for (int nt = 0; nt < 6; ++nt) {
    int col = w * 96 + nt * 16 + l16;
    const short8* bp = (const short8*)(wq + (size_t)col * 128 + quad * 8);
    f32x4 c = {0.f, 0.f, 0.f, 0.f};
#pragma unroll
    for (int kc = 0; kc < 4; ++kc)
      c = __builtin_amdgcn_mfma_f32_16x16x32_bf16(a[kc], bp[kc * 4], c, 0, 0, 0);
    float bv = qb[col];
#pragma unroll
    for (int r2 = 0; r2 < 4; ++r2)
      qkv[(size_t)(m0 + quad * 4 + r2) * 384 + col] = f2b(c[r2] + bv);
  }
}

// ---------- MFMA GEMM: C[M,N] = A[M,128] * W[N,128]^T + bias ----------
__global__ __launch_bounds__(256) void gemm_mfma(const unsigned short* __restrict__ A,
                                                 const unsigned short* __restrict__ W,
                                                 const float* __restrict__ bias,
                                                 unsigned short* __restrict__ Cmat,
                                                 int N) {
  int m0 = blockIdx.x * 64, n0 = blockIdx.y * 64;
  int tid = threadIdx.x;
  int w = tid >> 6, lane = tid & 63;
  int quad = lane >> 4, l16 = lane & 15;

  const short8* ap =
      (const short8*)(A + (size_t)(m0 + w * 16 + l16) * 128 + quad * 8);
  short8 a[4];
#pragma unroll
  for (int kc = 0; kc < 4; ++kc) a[kc] = ap[kc * 4];

  f32x4 acc[4];
#pragma unroll
  for (int nt = 0; nt < 4; ++nt) {
    const short8* bp =
        (const short8*)(W + (size_t)(n0 + nt * 16 + l16) * 128 + quad * 8);
    f32x4 c = {0.f, 0.f, 0.f, 0.f};
#pragma unroll
    for (int kc = 0; kc < 4; ++kc)
      c = __builtin_amdgcn_mfma_f32_16x16x32_bf16(a[kc], bp[kc * 4], c, 0, 0, 0);
    acc[nt] = c;
  }

#pragma unroll
  for (int nt = 0; nt < 4; ++nt) {
    int col = n0 + nt * 16 + l16;
    float bv = bias[col];
#pragma unroll
    for (int r = 0; r < 4; ++r) {
      int m = m0 + w * 16 + quad * 4 + r;
      Cmat[(size_t)m * N + col] = f2b(acc[nt][r] + bv);
    }
  }
}

// ---------- neighborhood attention v7 ----------
// grid (256 tiles, 2 head-pairs, 2 batch) = 1024 blocks; block 256 = 4 waves.
// tile = 4x4 px; halo 10x10 = 100 rows; 2 heads staged (stride 68 ushorts).
// thread: r=tid&7 (4 dims), hl=(tid>>3)&1, px=tid>>4 (0..15).
// Scores in LDS sc[32][50] (r==0 writes); 4 blocks/CU -> 16 waves/CU.
#define R7STRIDE 68
__global__ __launch_bounds__(256, 4) void na_attn(const unsigned short* __restrict__ qkvp,
                                                  const float* __restrict__ rpb,
                                                  unsigned short* __restrict__ out) {
  __shared__ __align__(16) unsigned short kbuf[100 * R7STRIDE];
  __shared__ __align__(16) unsigned short vbuf[100 * R7STRIDE];
  __shared__ float rb[338];
  __shared__ float sc[32][50];

  int ti = blockIdx.x >> 4, tj = blockIdx.x & 15;   // 16x16 tiles of 4x4 px
  int hp = blockIdx.y;
  int bz = blockIdx.z;
  int tid = threadIdx.x;
  int bi0 = ti * 4 - 3, bj0 = tj * 4 - 3;           // halo origin (10x10)

  for (int t = tid; t < 338; t += 256) rb[t] = rpb[hp * 338 + t];

  // stage K/V halo: 100 rows x 16 chunks of 16B (8 K + 8 V; 2 heads x 32 d)
  for (int t = tid; t < 1600; t += 256) {
    int row = t >> 4;            // 0..99
    int sub = t & 15;
    int isv = sub >> 3;          // 0=K, 1=V
    int c = sub & 7;             // chunk within the 2-head slice (64 ushorts)
    int ri = row / 10, rj = row - ri * 10;
    int gi = bi0 + ri, gj = bj0 + rj;
    uint4 val = make_uint4(0, 0, 0, 0);
    if ((unsigned)gi < 64u && (unsigned)gj < 64u) {
      int pixn = (bz * 64 + gi) * 64 + gj;
      val = *(const uint4*)(qkvp + (size_t)pixn * 384 + 128 + isv * 128 +
                            hp * 64 + c * 8);
    }
    *(uint4*)((isv ? vbuf : kbuf) + row * R7STRIDE + c * 8) = val;
  }
  __syncthreads();

  int r = tid & 7;               // dim chunk (4 dims)
  int hl = (tid >> 3) & 1;       // local head
  int px = tid >> 4;             // 0..15
  int ph = px * 2 + hl;          // slot 0..31
  int pi = px >> 2, pj = px & 3;
  int i = ti * 4 + pi, j = tj * 4 + pj;
  int si = min(max(i - 3, 0), 57), sj = min(max(j - 3, 0), 57);
  int li = si - bi0, lj = sj - bj0;
  int oi = i - si, oj = j - sj;
  int H = hp * 2 + hl;
  int pix = (bz * 64 + i) * 64 + j;

  const float scale = 0.17677669529663687f;   // 32^-0.5
  float q[4];
  {
    uint2 t = *(const uint2*)(qkvp + (size_t)pix * 384 + H * 32 + r * 4);
    q[0] = bflo(t.x) * scale;  q[1] = bfhi(t.x) * scale;
    q[2] = bflo(t.y) * scale;  q[3] = bfhi(t.y) * scale;
  }

  const unsigned short* kh = kbuf + hl * 32 + r * 4;
  const unsigned short* vh = vbuf + hl * 32 + r * 4;
  const float* rbh = rb + hl * 169;

  // scores -> LDS: 4-dim partial dot, 8-lane butterfly (r bits), r==0 stores
#pragma unroll
  for (int p = 0; p < 7; ++p) {
#pragma unroll
    for (int qq = 0; qq < 7; ++qq) {
      int n = (li + p) * 10 + (lj + qq);
      uint2 t = *(const uint2*)(kh + n * R7STRIDE);
      float dot = q[0] * bflo(t.x) + q[1] * bfhi(t.x)
                + q[2] * bflo(t.y) + q[3] * bfhi(t.y);
      dot += __shfl_xor(dot, 1);
      dot += __shfl_xor(dot, 2);
      dot += __shfl_xor(dot, 4);
      if (r == 0) sc[ph][p * 7 + qq] = dot + rbh[(p + 6 - oi) * 13 + (qq + 6 - oj)];
    }
  }
  __syncthreads();

  // pass 1: max
  float m = -INFINITY;
#pragma unroll
  for (int n = 0; n < 49; ++n) m = fmaxf(m, sc[ph][n]);

  // pass 2: fused exp/sum + P@V over this lane's 4 dims
  float sum = 0.f;
  float acc[4] = {0.f, 0.f, 0.f, 0.f};
#pragma unroll
  for (int p = 0; p < 7; ++p) {
#pragma unroll
    for (int qq = 0; qq < 7; ++qq) {
      float e = __expf(sc[ph][p * 7 + qq] - m);
      sum += e;
      int n = (li + p) * 10 + (lj + qq);
      uint2 t = *(const uint2*)(vh + n * R7STRIDE);
      acc[0] += e * bflo(t.x);  acc[1] += e * bfhi(t.x);
      acc[2] += e * bflo(t.y);  acc[3] += e * bfhi(t.y);
    }
  }
  float inv = 1.f / sum;
  uint2 t;
  t.x = pack2(acc[0] * inv, acc[1] * inv);
  t.y = pack2(acc[2] * inv, acc[3] * inv);
  *(uint2*)(out + (size_t)pix * 128 + H * 32 + r * 4) = t;
}

// ---------- LayerNorm over C + transpose to (B,C,H,W), fp32 store ----------
__global__ __launch_bounds__(256) void ln_out(const unsigned short* __restrict__ y,
                                              const float* __restrict__ g,
                                              const float* __restrict__ bta,
                                              float* __restrict__ out) {
  __shared__ float tile[64][129];
  __shared__ float mean_s[64], rstd_s[64];
  int blk = blockIdx.x;
  int b = blk >> 6, i = blk & 63;
  int tid = threadIdx.x;
  const unsigned short* yrow = y + (size_t)blk * 64 * 128;
  for (int idx = tid; idx < 8192; idx += 256) {
    int j = idx >> 7, c = idx & 127;
    tile[j][c] = __uint_as_float((unsigned)yrow[idx] << 16);
  }
  __syncthreads();
  int jj = tid >> 2, qtr = tid & 3;
  float sum = 0.f, sumsq = 0.f;
#pragma unroll
  for (int cc = 0; cc < 32; ++cc) {
    float v = tile[jj][qtr * 32 + cc];
    sum += v; sumsq += v * v;
  }
  sum += __shfl_xor(sum, 1);  sum += __shfl_xor(sum, 2);
  sumsq += __shfl_xor(sumsq, 1);  sumsq += __shfl_xor(sumsq, 2);
  if (qtr == 0) {
    float mu = sum * (1.f / 128.f);
    mean_s[jj] = mu;
    rstd_s[jj] = rsqrtf(sumsq * (1.f / 128.f) - mu * mu + 1e-5f);
  }
  __syncthreads();
  int c0 = tid >> 6;
  int j = tid & 63;
  for (int c = c0; c < 128; c += 4) {
    float v = (tile[j][c] - mean_s[j]) * rstd_s[j] * g[c] + bta[c];
    out[(((size_t)b * 128 + c) * 64 + i) * 64 + j] = v;
  }
}

extern "C" void kernel_launch(void* const* d_in, const int* in_sizes, int n_in,
                              void* d_out, int out_size, void* d_ws, size_t ws_size,
                              hipStream_t stream) {
  (void)in_sizes; (void)n_in; (void)out_size; (void)ws_size;
  const float* x   = (const float*)d_in[0];
  const float* qw  = (const float*)d_in[1];   // (2,384,128)
  const float* qb  = (const float*)d_in[2];   // (2,384)
  const float* rpb = (const float*)d_in[3];   // (2,4,13,13)
  const float* pw  = (const float*)d_in[4];   // (2,128,128)
  const float* pb  = (const float*)d_in[5];   // (2,128)
  const float* lg  = (const float*)d_in[6];
  const float* lb  = (const float*)d_in[7];

  unsigned short* y    = (unsigned short*)d_ws;          // proj outputs (2 MB)
  unsigned short* qkv  = y + (size_t)PIX * 128;          // PIX*384 (6 MB)
  unsigned short* wq   = qkv + (size_t)PIX * 384;        // 98304
  unsigned short* wp   = wq + 98304;                     // 32768
  unsigned short* attn = (unsigned short*)d_out;         // PIX*128 (scratch)
  float* out = (float*)d_out;

  cvtw<<<384, 256, 0, stream>>>(qw, pw, wq, wp);
  xqkv<<<512, 256, 0, stream>>>(x, wq, qb, qkv);                          // qkv0
  na_attn<<<dim3(256, 2, 2), 256, 0, stream>>>(qkv, rpb, attn);           // attn0
  gemm_mfma<<<dim3(128, 2), 256, 0, stream>>>(attn, wp, pb, y, 128);      // proj0
  gemm_mfma<<<dim3(128, 6), 256, 0, stream>>>(y, wq + 49152, qb + 384, qkv, 384); // qkv1
  na_attn<<<dim3(256, 2, 2), 256, 0, stream>>>(qkv, rpb + 676, attn);     // attn1
  gemm_mfma<<<dim3(128, 2), 256, 0, stream>>>(attn, wp + 16384, pb + 128, y, 128); // proj1
  ln_out<<<128, 256, 0, stream>>>(y, lg, lb, out);
}